// Round 6
// baseline (11174.073 us; speedup 1.0000x reference)
//
#include <hip/hip_runtime.h>
#include <hip/hip_cooperative_groups.h>
#include <cstdint>
#include <cstddef>
#include <cstring>

namespace cg = cooperative_groups;

#define H 8192
#define NNZ 1000000
#define B 128
#define T 64

typedef unsigned int u32;
typedef float f32x4 __attribute__((ext_vector_type(4)));

__device__ inline float bf_lo(u32 w) { return __uint_as_float(w << 16); }
__device__ inline float bf_hi(u32 w) { return __uint_as_float(w & 0xffff0000u); }
__device__ inline unsigned short f2bf(float f) {        // RNE float->bf16
    u32 v = __float_as_uint(f);
    v += 0x7fffu + ((v >> 16) & 1u);
    return (unsigned short)(v >> 16);
}
__device__ inline u32 pack_bf16(float a, float b) {
    return (u32)f2bf(a) | ((u32)f2bf(b) << 16);
}
__device__ inline float fast_tanh(float x) {
    float e = __expf(2.0f * x);
    return 1.0f - 2.0f / (e + 1.0f);
}

// ---------------- CSR build ----------------
__global__ void hist_kernel(const int* __restrict__ rows, int nnz, int* __restrict__ count) {
    int j = blockIdx.x * blockDim.x + threadIdx.x;
    if (j < nnz) atomicAdd(&count[rows[j]], 1);
}

__global__ void scan_kernel(const int* __restrict__ cnt0, int* __restrict__ rp0, int* __restrict__ cur0,
                            const int* __restrict__ cnt1, int* __restrict__ rp1, int* __restrict__ cur1) {
    const int* cnt = (blockIdx.x == 0) ? cnt0 : cnt1;
    int* rp  = (blockIdx.x == 0) ? rp0 : rp1;
    int* cur = (blockIdx.x == 0) ? cur0 : cur1;
    __shared__ int buf[1024];
    __shared__ int carry;
    int tid = threadIdx.x;
    if (tid == 0) carry = 0;
    __syncthreads();
    for (int base = 0; base < H; base += 1024) {
        int v = cnt[base + tid];
        buf[tid] = v;
        __syncthreads();
        for (int off = 1; off < 1024; off <<= 1) {
            int t = (tid >= off) ? buf[tid - off] : 0;
            __syncthreads();
            buf[tid] += t;
            __syncthreads();
        }
        int incl = buf[tid];
        int excl = incl - v;
        int c = carry;
        rp[base + tid]  = c + excl;
        cur[base + tid] = c + excl;
        __syncthreads();
        if (tid == 1023) carry = c + incl;
        __syncthreads();
    }
    if (tid == 0) rp[H] = carry;
}

__global__ void scatter_kernel(const int* __restrict__ rows, const int* __restrict__ cols,
                               const float* __restrict__ vals, int nnz,
                               int* __restrict__ cursor, int2* __restrict__ opair) {
    int j = blockIdx.x * blockDim.x + threadIdx.x;
    if (j < nnz) {
        int r = rows[j];
        int p = atomicAdd(&cursor[r], 1);
        opair[p] = make_int2(cols[j], __float_as_int(vals[j]));
    }
}

// ---------------- fp32 transpose src[R][C] -> dst[C][R] ----------------
__global__ void transpose_kernel(const float* __restrict__ src, float* __restrict__ dst,
                                 int R, int C) {
    __shared__ float tile[32][33];
    int c0 = blockIdx.x * 32, r0 = blockIdx.y * 32;
    int x = threadIdx.x, y = threadIdx.y;
    #pragma unroll
    for (int i = y; i < 32; i += 8) {
        tile[i][x] = src[(size_t)(r0 + i) * C + (c0 + x)];
    }
    __syncthreads();
    #pragma unroll
    for (int i = y; i < 32; i += 8) {
        dst[(size_t)(c0 + i) * R + (r0 + x)] = tile[x][i];
    }
}

// ---------------- transpose + bf16-pack: x [B][T*H] fp32 -> xTb [T*H][64] u32 (bf16 pairs) ----------------
__global__ void transpose_bf16_kernel(const float* __restrict__ src, u32* __restrict__ dst) {
    __shared__ float tile[32][33];
    int c0 = blockIdx.x * 32;    // T*H dim
    int r0 = blockIdx.y * 32;    // B dim
    int x = threadIdx.x, y = threadIdx.y;
    #pragma unroll
    for (int i = y; i < 32; i += 8) {
        tile[i][x] = src[(size_t)(r0 + i) * (T * H) + (c0 + x)];
    }
    __syncthreads();
    int tid = y * 32 + x;        // 256 threads, 512 words to write
    #pragma unroll
    for (int idx = tid; idx < 32 * 16; idx += 256) {
        int row = idx >> 4, w = idx & 15;
        u32 word = pack_bf16(tile[2 * w][row], tile[2 * w + 1][row]);
        dst[(size_t)(c0 + row) * 64 + (r0 >> 1) + w] = word;
    }
}

// ---------------- ih precompute: pre[t,h,:] = bias + spmm(ih, x_t) ----------------
// 1 wave/row, blockIdx-only row derivation (scalar CSR stream), XCD swizzle (XCD k owns
// t in [8k,8k+8)). Gathers: bf16, 2 columns per instruction (lanes 0-31: even nnz col,
// lanes 32-63: odd nnz col), float4 accumulators, shfl_xor(32) combine.
// NOTE (R5 post-mortem): this kernel is at a measured dual wall — TCP line-service
// ~2.4 cyc/line/CU (256M lines => ~955us) == VALU (~910us). Don't touch without
// cutting BOTH lines/nnz and VALU/nnz.
__global__ void __launch_bounds__(64) ih_pre_kernel(
    const int* __restrict__ rp, const int2* __restrict__ pair,
    const u32* __restrict__ xTb, float* __restrict__ pre,
    const float* __restrict__ bias_ih, const float* __restrict__ bias_hh) {
    int bid = blockIdx.x;
    int xcd = bid & 7;
    int i0  = bid >> 3;
    int t   = (xcd << 3) + (i0 >> 13);
    int r   = i0 & (H - 1);
    int lane = threadIdx.x;
    bool hi = lane >= 32;
    int i = lane & 31;
    const uint2* __restrict__ xt = (const uint2*)(xTb + (size_t)t * H * 64);
    f32x4 acc = {0.f, 0.f, 0.f, 0.f};
    int s = rp[r], e = rp[r + 1];
    int j = s;
    for (; j + 16 <= e; j += 16) {
        int2 q[16];
        #pragma unroll
        for (int u = 0; u < 16; ++u) q[u] = pair[j + u];
        uint2 g[8];
        #pragma unroll
        for (int u = 0; u < 8; ++u) {
            int c = hi ? q[2 * u + 1].x : q[2 * u].x;
            g[u] = xt[(size_t)c * 32 + i];
        }
        #pragma unroll
        for (int u = 0; u < 8; ++u) {
            float v = __int_as_float(hi ? q[2 * u + 1].y : q[2 * u].y);
            acc.x = fmaf(v, bf_lo(g[u].x), acc.x);
            acc.y = fmaf(v, bf_hi(g[u].x), acc.y);
            acc.z = fmaf(v, bf_lo(g[u].y), acc.z);
            acc.w = fmaf(v, bf_hi(g[u].y), acc.w);
        }
    }
    for (; j + 2 <= e; j += 2) {
        int2 q0 = pair[j], q1 = pair[j + 1];
        int c = hi ? q1.x : q0.x;
        uint2 g = xt[(size_t)c * 32 + i];
        float v = __int_as_float(hi ? q1.y : q0.y);
        acc.x = fmaf(v, bf_lo(g.x), acc.x);
        acc.y = fmaf(v, bf_hi(g.x), acc.y);
        acc.z = fmaf(v, bf_lo(g.y), acc.z);
        acc.w = fmaf(v, bf_hi(g.y), acc.w);
    }
    if (j < e) {
        int2 q0 = pair[j];
        uint2 g = xt[(size_t)q0.x * 32 + i];
        float v = hi ? 0.0f : __int_as_float(q0.y);
        acc.x = fmaf(v, bf_lo(g.x), acc.x);
        acc.y = fmaf(v, bf_hi(g.x), acc.y);
        acc.z = fmaf(v, bf_lo(g.y), acc.z);
        acc.w = fmaf(v, bf_hi(g.y), acc.w);
    }
    f32x4 tot;
    tot.x = acc.x + __shfl_xor(acc.x, 32, 64);
    tot.y = acc.y + __shfl_xor(acc.y, 32, 64);
    tot.z = acc.z + __shfl_xor(acc.z, 32, 64);
    tot.w = acc.w + __shfl_xor(acc.w, 32, 64);
    if (lane < 32) {
        float bias = bias_ih[r] + bias_hh[r];
        tot.x += bias; tot.y += bias; tot.z += bias; tot.w += bias;
        __builtin_nontemporal_store(tot, (f32x4*)(pre + ((size_t)t * H + r) * B) + i);
    }
}

// ---------------- fused recurrence: all 64 steps in one cooperative kernel ----------------
// 4 waves/block, one row per wave (readfirstlane keeps the CSR stream scalar).
// grid.sync() between steps replaces 64 kernel launches.
__global__ void __launch_bounds__(256, 8) coop_steps_kernel(
    const int* __restrict__ rp, const int2* __restrict__ pair,
    u32* __restrict__ ha, u32* __restrict__ hb, float* __restrict__ pre) {
    cg::grid_group grid = cg::this_grid();
    const int tid  = threadIdx.x;
    const int wav  = tid >> 6;
    const int lane = tid & 63;
    const bool hi  = lane >= 32;
    const int i    = lane & 31;
    const int rstride = (int)(gridDim.x << 2);
    u32* hp = ha;
    u32* hn = hb;
    for (int t = 0; t < T; ++t) {
        float* __restrict__ pre_t = pre + (size_t)t * H * B;
        const uint2* __restrict__ h2 = (const uint2*)hp;
        for (int r0 = ((int)blockIdx.x << 2) + wav; r0 < H; r0 += rstride) {
            const int r = __builtin_amdgcn_readfirstlane(r0);
            f32x4 acc = {0.f, 0.f, 0.f, 0.f};
            int s = rp[r], e = rp[r + 1];
            int j = s;
            for (; j + 16 <= e; j += 16) {
                int2 q[16];
                #pragma unroll
                for (int u = 0; u < 16; ++u) q[u] = pair[j + u];
                uint2 g[8];
                #pragma unroll
                for (int u = 0; u < 8; ++u) {
                    int c = hi ? q[2 * u + 1].x : q[2 * u].x;
                    g[u] = h2[(size_t)c * 32 + i];
                }
                #pragma unroll
                for (int u = 0; u < 8; ++u) {
                    float v = __int_as_float(hi ? q[2 * u + 1].y : q[2 * u].y);
                    acc.x = fmaf(v, bf_lo(g[u].x), acc.x);
                    acc.y = fmaf(v, bf_hi(g[u].x), acc.y);
                    acc.z = fmaf(v, bf_lo(g[u].y), acc.z);
                    acc.w = fmaf(v, bf_hi(g[u].y), acc.w);
                }
            }
            for (; j + 2 <= e; j += 2) {
                int2 q0 = pair[j], q1 = pair[j + 1];
                int c = hi ? q1.x : q0.x;
                uint2 g = h2[(size_t)c * 32 + i];
                float v = __int_as_float(hi ? q1.y : q0.y);
                acc.x = fmaf(v, bf_lo(g.x), acc.x);
                acc.y = fmaf(v, bf_hi(g.x), acc.y);
                acc.z = fmaf(v, bf_lo(g.y), acc.z);
                acc.w = fmaf(v, bf_hi(g.y), acc.w);
            }
            if (j < e) {
                int2 q0 = pair[j];
                uint2 g = h2[(size_t)q0.x * 32 + i];
                float v = hi ? 0.0f : __int_as_float(q0.y);
                acc.x = fmaf(v, bf_lo(g.x), acc.x);
                acc.y = fmaf(v, bf_hi(g.x), acc.y);
                acc.z = fmaf(v, bf_lo(g.y), acc.z);
                acc.w = fmaf(v, bf_hi(g.y), acc.w);
            }
            f32x4 tot;
            tot.x = acc.x + __shfl_xor(acc.x, 32, 64);
            tot.y = acc.y + __shfl_xor(acc.y, 32, 64);
            tot.z = acc.z + __shfl_xor(acc.z, 32, 64);
            tot.w = acc.w + __shfl_xor(acc.w, 32, 64);
            if (lane < 32) {
                f32x4 p = __builtin_nontemporal_load((const f32x4*)(pre_t + (size_t)r * B) + i);
                float h0 = fast_tanh(tot.x + p.x);
                float h1 = fast_tanh(tot.y + p.y);
                float h2v = fast_tanh(tot.z + p.z);
                float h3 = fast_tanh(tot.w + p.w);
                f32x4 o = {h0, h1, h2v, h3};
                __builtin_nontemporal_store(o, (f32x4*)(pre_t + (size_t)r * B) + i);  // outT (fp32)
                uint2 hw;
                hw.x = pack_bf16(h0, h1);
                hw.y = pack_bf16(h2v, h3);
                ((uint2*)hn)[(size_t)r * 32 + i] = hw;   // next-step operand (bf16)
            }
        }
        grid.sync();
        u32* tmp = hp; hp = hn; hn = tmp;
    }
}

extern "C" void kernel_launch(void* const* d_in, const int* in_sizes, int n_in,
                              void* d_out, int out_size, void* d_ws, size_t ws_size,
                              hipStream_t stream) {
    const float* x        = (const float*)d_in[0];
    const int*   ih_idx   = (const int*)d_in[1];
    const float* ih_val   = (const float*)d_in[2];
    const int*   hh_idx   = (const int*)d_in[3];
    const float* hh_val   = (const float*)d_in[4];
    const float* bias_ih  = (const float*)d_in[5];
    const float* bias_hh  = (const float*)d_in[6];
    const int* ih_rows = ih_idx;
    const int* ih_cols = ih_idx + NNZ;
    const int* hh_rows = hh_idx;
    const int* hh_cols = hh_idx + NNZ;

    char* ws = (char*)d_ws;
    size_t off = 0;
    auto alloc = [&](size_t bytes) -> void* {
        void* p = ws + off;
        off += (bytes + 255) & ~(size_t)255;
        return p;
    };
    u32*   xTb     = (u32*)  alloc((size_t)T * H * 64 * 4);  // 128 MB bf16-packed
    float* pre     = (float*)alloc((size_t)T * H * B * 4);   // 256 MB (becomes outT)
    int2*  pair_ih = (int2*) alloc((size_t)NNZ * 8);
    int2*  pair_hh = (int2*) alloc((size_t)NNZ * 8);
    int*   rp_ih   = (int*)  alloc((size_t)(H + 1) * 4);
    int*   rp_hh   = (int*)  alloc((size_t)(H + 1) * 4);
    int*   cnt_ih  = (int*)  alloc((size_t)H * 4);
    int*   cnt_hh  = (int*)  alloc((size_t)H * 4);
    int*   cur_ih  = (int*)  alloc((size_t)H * 4);
    int*   cur_hh  = (int*)  alloc((size_t)H * 4);
    u32*   h0      = (u32*)  alloc((size_t)H * 64 * 4);      // bf16-packed h
    u32*   h1      = (u32*)  alloc((size_t)H * 64 * 4);

    hipMemsetAsync(cnt_ih, 0, (size_t)H * 4, stream);
    hipMemsetAsync(cnt_hh, 0, (size_t)H * 4, stream);
    hipMemsetAsync(h0, 0, (size_t)H * 64 * 4, stream);

    const int tb = 256;
    const int gb = (NNZ + tb - 1) / tb;
    hist_kernel<<<gb, tb, 0, stream>>>(ih_rows, NNZ, cnt_ih);
    hist_kernel<<<gb, tb, 0, stream>>>(hh_rows, NNZ, cnt_hh);
    scan_kernel<<<2, 1024, 0, stream>>>(cnt_ih, rp_ih, cur_ih, cnt_hh, rp_hh, cur_hh);
    scatter_kernel<<<gb, tb, 0, stream>>>(ih_rows, ih_cols, ih_val, NNZ, cur_ih, pair_ih);
    scatter_kernel<<<gb, tb, 0, stream>>>(hh_rows, hh_cols, hh_val, NNZ, cur_hh, pair_hh);

    // x [B][T*H] fp32 -> xTb [T*H][64] bf16-pairs
    dim3 tblk(32, 8);
    dim3 tgrid1((T * H) / 32, B / 32);
    transpose_bf16_kernel<<<tgrid1, tblk, 0, stream>>>(x, xTb);

    // all-timestep ih spmm + bias
    ih_pre_kernel<<<T * H, 64, 0, stream>>>(rp_ih, pair_ih, xTb, pre, bias_ih, bias_hh);

    // fused sequential recurrence (one cooperative kernel, grid.sync between steps)
    {
        int maxB = 0;
        hipOccupancyMaxActiveBlocksPerMultiprocessor(&maxB, (const void*)coop_steps_kernel, 256, 0);
        int nblk = maxB * 256;          // 256 CUs
        if (nblk > 2048) nblk = 2048;   // 2048*4 waves = 8192 rows, one row/wave
        if (nblk < 64)   nblk = 64;     // safety fallback (row loop handles any grid)
        const int* rp_a = rp_hh; const int2* pair_a = pair_hh;
        u32* ha = h0; u32* hb = h1; float* pre_a = pre;
        void* args[] = { (void*)&rp_a, (void*)&pair_a, (void*)&ha, (void*)&hb, (void*)&pre_a };
        hipLaunchCooperativeKernel((const void*)coop_steps_kernel, dim3(nblk), dim3(256),
                                   args, 0, stream);
    }

    // outT [T*H][B] -> d_out [B][T*H]
    dim3 tgrid2(B / 32, (T * H) / 32);
    transpose_kernel<<<tgrid2, tblk, 0, stream>>>(pre, (float*)d_out, T * H, B);
}

// Round 8
// 2622.137 us; speedup vs baseline: 4.2614x; 4.2614x over previous
//
#include <hip/hip_runtime.h>
#include <cstdint>
#include <cstddef>
#include <cstring>

#define H 8192
#define NNZ 1000000
#define B 128
#define T 64

typedef unsigned int u32;
typedef float f32x4 __attribute__((ext_vector_type(4)));
typedef u32 u32x2 __attribute__((ext_vector_type(2)));

__device__ inline float bf_lo(u32 w) { return __uint_as_float(w << 16); }
__device__ inline float bf_hi(u32 w) { return __uint_as_float(w & 0xffff0000u); }
__device__ inline unsigned short f2bf(float f) {        // RNE float->bf16
    u32 v = __float_as_uint(f);
    v += 0x7fffu + ((v >> 16) & 1u);
    return (unsigned short)(v >> 16);
}
__device__ inline u32 pack_bf16(float a, float b) {
    return (u32)f2bf(a) | ((u32)f2bf(b) << 16);
}
__device__ inline float fast_tanh(float x) {
    float e = __expf(2.0f * x);
    return 1.0f - 2.0f / (e + 1.0f);
}

// ---------------- CSR build ----------------
__global__ void hist_kernel(const int* __restrict__ rows, int nnz, int* __restrict__ count) {
    int j = blockIdx.x * blockDim.x + threadIdx.x;
    if (j < nnz) atomicAdd(&count[rows[j]], 1);
}

__global__ void scan_kernel(const int* __restrict__ cnt0, int* __restrict__ rp0, int* __restrict__ cur0,
                            const int* __restrict__ cnt1, int* __restrict__ rp1, int* __restrict__ cur1) {
    const int* cnt = (blockIdx.x == 0) ? cnt0 : cnt1;
    int* rp  = (blockIdx.x == 0) ? rp0 : rp1;
    int* cur = (blockIdx.x == 0) ? cur0 : cur1;
    __shared__ int buf[1024];
    __shared__ int carry;
    int tid = threadIdx.x;
    if (tid == 0) carry = 0;
    __syncthreads();
    for (int base = 0; base < H; base += 1024) {
        int v = cnt[base + tid];
        buf[tid] = v;
        __syncthreads();
        for (int off = 1; off < 1024; off <<= 1) {
            int t = (tid >= off) ? buf[tid - off] : 0;
            __syncthreads();
            buf[tid] += t;
            __syncthreads();
        }
        int incl = buf[tid];
        int excl = incl - v;
        int c = carry;
        rp[base + tid]  = c + excl;
        cur[base + tid] = c + excl;
        __syncthreads();
        if (tid == 1023) carry = c + incl;
        __syncthreads();
    }
    if (tid == 0) rp[H] = carry;
}

__global__ void scatter_kernel(const int* __restrict__ rows, const int* __restrict__ cols,
                               const float* __restrict__ vals, int nnz,
                               int* __restrict__ cursor, int2* __restrict__ opair) {
    int j = blockIdx.x * blockDim.x + threadIdx.x;
    if (j < nnz) {
        int r = rows[j];
        int p = atomicAdd(&cursor[r], 1);
        opair[p] = make_int2(cols[j], __float_as_int(vals[j]));
    }
}

// ---------------- transpose + bf16-pack: x [B][T*H] fp32 -> xTb [T*H][64] u32 (bf16 pairs) ----------------
__global__ void transpose_bf16_kernel(const float* __restrict__ src, u32* __restrict__ dst) {
    __shared__ float tile[32][33];
    int c0 = blockIdx.x * 32;    // T*H dim
    int r0 = blockIdx.y * 32;    // B dim
    int x = threadIdx.x, y = threadIdx.y;
    #pragma unroll
    for (int i = y; i < 32; i += 8) {
        tile[i][x] = src[(size_t)(r0 + i) * (T * H) + (c0 + x)];
    }
    __syncthreads();
    int tid = y * 32 + x;        // 256 threads, 512 words to write
    #pragma unroll
    for (int idx = tid; idx < 32 * 16; idx += 256) {
        int row = idx >> 4, w = idx & 15;
        u32 word = pack_bf16(tile[2 * w][row], tile[2 * w + 1][row]);
        dst[(size_t)(c0 + row) * 64 + (r0 >> 1) + w] = word;
    }
}

// ---------------- final transpose: outb [T*H][64] u32 (bf16 pairs) -> d_out [B][T*H] f32 ----------------
__global__ void transpose_out_kernel(const u32* __restrict__ src, float* __restrict__ dst) {
    __shared__ u32 tile[32][33];
    int c0 = blockIdx.x * 32;    // flat T*H index base
    int w0 = blockIdx.y * 32;    // u32-word (batch-pair) index base
    int x = threadIdx.x, y = threadIdx.y;
    #pragma unroll
    for (int i = y; i < 32; i += 8) {
        tile[i][x] = src[(size_t)(c0 + i) * 64 + (w0 + x)];
    }
    __syncthreads();
    #pragma unroll
    for (int i = y; i < 64; i += 8) {
        int w = i >> 1;
        u32 word = tile[x][w];
        float val = (i & 1) ? bf_hi(word) : bf_lo(word);
        dst[(size_t)(2 * w0 + i) * (size_t)(T * H) + (c0 + x)] = val;
    }
}

// ---------------- ih precompute: pre[t,h,:] = bias + spmm(ih, x_t), bf16-packed output ----------------
// 1 wave/row, blockIdx-only row derivation (scalar CSR stream), XCD swizzle (XCD k owns
// t in [8k,8k+8) so its 2MB x-slice stays L2-resident). Gathers: bf16, 2 columns per
// instruction (lane halves), f32x4 accumulators, shfl_xor(32) combine.
// NOTE (R5 post-mortem): gather path at measured dual wall — TCP line-service
// ~2.4 cyc/line/CU (256M lines => ~1000us) == VALU (~910us). Don't touch without
// cutting BOTH lines/nnz and VALU/nnz.
__global__ void __launch_bounds__(64) ih_pre_kernel(
    const int* __restrict__ rp, const int2* __restrict__ pair,
    const u32* __restrict__ xTb, u32* __restrict__ pre,
    const float* __restrict__ bias_ih, const float* __restrict__ bias_hh) {
    int bid = blockIdx.x;
    int xcd = bid & 7;
    int i0  = bid >> 3;
    int t   = (xcd << 3) + (i0 >> 13);
    int r   = i0 & (H - 1);
    int lane = threadIdx.x;
    bool hi = lane >= 32;
    int i = lane & 31;
    const uint2* __restrict__ xt = (const uint2*)(xTb + (size_t)t * H * 64);
    f32x4 acc = {0.f, 0.f, 0.f, 0.f};
    int s = rp[r], e = rp[r + 1];
    int j = s;
    for (; j + 16 <= e; j += 16) {
        int2 q[16];
        #pragma unroll
        for (int u = 0; u < 16; ++u) q[u] = pair[j + u];
        uint2 g[8];
        #pragma unroll
        for (int u = 0; u < 8; ++u) {
            int c = hi ? q[2 * u + 1].x : q[2 * u].x;
            g[u] = xt[(size_t)c * 32 + i];
        }
        #pragma unroll
        for (int u = 0; u < 8; ++u) {
            float v = __int_as_float(hi ? q[2 * u + 1].y : q[2 * u].y);
            acc.x = fmaf(v, bf_lo(g[u].x), acc.x);
            acc.y = fmaf(v, bf_hi(g[u].x), acc.y);
            acc.z = fmaf(v, bf_lo(g[u].y), acc.z);
            acc.w = fmaf(v, bf_hi(g[u].y), acc.w);
        }
    }
    for (; j + 2 <= e; j += 2) {
        int2 q0 = pair[j], q1 = pair[j + 1];
        int c = hi ? q1.x : q0.x;
        uint2 g = xt[(size_t)c * 32 + i];
        float v = __int_as_float(hi ? q1.y : q0.y);
        acc.x = fmaf(v, bf_lo(g.x), acc.x);
        acc.y = fmaf(v, bf_hi(g.x), acc.y);
        acc.z = fmaf(v, bf_lo(g.y), acc.z);
        acc.w = fmaf(v, bf_hi(g.y), acc.w);
    }
    if (j < e) {
        int2 q0 = pair[j];
        uint2 g = xt[(size_t)q0.x * 32 + i];
        float v = hi ? 0.0f : __int_as_float(q0.y);
        acc.x = fmaf(v, bf_lo(g.x), acc.x);
        acc.y = fmaf(v, bf_hi(g.x), acc.y);
        acc.z = fmaf(v, bf_lo(g.y), acc.z);
        acc.w = fmaf(v, bf_hi(g.y), acc.w);
    }
    f32x4 tot;
    tot.x = acc.x + __shfl_xor(acc.x, 32, 64);
    tot.y = acc.y + __shfl_xor(acc.y, 32, 64);
    tot.z = acc.z + __shfl_xor(acc.z, 32, 64);
    tot.w = acc.w + __shfl_xor(acc.w, 32, 64);
    if (lane < 32) {
        float bias = bias_ih[r] + bias_hh[r];
        u32x2 pw;
        pw.x = pack_bf16(tot.x + bias, tot.y + bias);
        pw.y = pack_bf16(tot.z + bias, tot.w + bias);
        __builtin_nontemporal_store(pw, (u32x2*)(pre + ((size_t)t * H + r) * 64) + i);
    }
}

// ---------------- one recurrence step ----------------
// 4 waves/block, one row per wave (readfirstlane keeps CSR stream scalar — proven in R6
// coop kernel: VGPR stayed 32). h lives ONLY in outb (bf16): step t writes outb[t] once;
// step t+1 gathers from it. hprev==nullptr => step 0 (h=0): tanh(pre) only.
__global__ void __launch_bounds__(256) step_kernel(
    const int* __restrict__ rp, const int2* __restrict__ pair,
    const u32* __restrict__ hprev, u32* __restrict__ hout,
    const u32* __restrict__ pre_t) {
    const int tid  = threadIdx.x;
    const int wav  = tid >> 6;
    const int lane = tid & 63;
    const bool hi  = lane >= 32;
    const int i    = lane & 31;
    const int r = __builtin_amdgcn_readfirstlane(((int)blockIdx.x << 2) + wav);
    // hoisted pre load: overlaps with gather latency
    u32x2 pw = __builtin_nontemporal_load((const u32x2*)pre_t + (size_t)r * 32 + i);
    f32x4 acc = {0.f, 0.f, 0.f, 0.f};
    if (hprev) {
        const uint2* __restrict__ h2 = (const uint2*)hprev;
        int s = rp[r], e = rp[r + 1];
        int j = s;
        for (; j + 16 <= e; j += 16) {
            int2 q[16];
            #pragma unroll
            for (int u = 0; u < 16; ++u) q[u] = pair[j + u];
            uint2 g[8];
            #pragma unroll
            for (int u = 0; u < 8; ++u) {
                int c = hi ? q[2 * u + 1].x : q[2 * u].x;
                g[u] = h2[(size_t)c * 32 + i];
            }
            #pragma unroll
            for (int u = 0; u < 8; ++u) {
                float v = __int_as_float(hi ? q[2 * u + 1].y : q[2 * u].y);
                acc.x = fmaf(v, bf_lo(g[u].x), acc.x);
                acc.y = fmaf(v, bf_hi(g[u].x), acc.y);
                acc.z = fmaf(v, bf_lo(g[u].y), acc.z);
                acc.w = fmaf(v, bf_hi(g[u].y), acc.w);
            }
        }
        for (; j + 2 <= e; j += 2) {
            int2 q0 = pair[j], q1 = pair[j + 1];
            int c = hi ? q1.x : q0.x;
            uint2 g = h2[(size_t)c * 32 + i];
            float v = __int_as_float(hi ? q1.y : q0.y);
            acc.x = fmaf(v, bf_lo(g.x), acc.x);
            acc.y = fmaf(v, bf_hi(g.x), acc.y);
            acc.z = fmaf(v, bf_lo(g.y), acc.z);
            acc.w = fmaf(v, bf_hi(g.y), acc.w);
        }
        if (j < e) {
            int2 q0 = pair[j];
            uint2 g = h2[(size_t)q0.x * 32 + i];
            float v = hi ? 0.0f : __int_as_float(q0.y);
            acc.x = fmaf(v, bf_lo(g.x), acc.x);
            acc.y = fmaf(v, bf_hi(g.x), acc.y);
            acc.z = fmaf(v, bf_lo(g.y), acc.z);
            acc.w = fmaf(v, bf_hi(g.y), acc.w);
        }
        acc.x += __shfl_xor(acc.x, 32, 64);
        acc.y += __shfl_xor(acc.y, 32, 64);
        acc.z += __shfl_xor(acc.z, 32, 64);
        acc.w += __shfl_xor(acc.w, 32, 64);
    }
    if (lane < 32) {
        float h0 = fast_tanh(acc.x + bf_lo(pw.x));
        float h1 = fast_tanh(acc.y + bf_hi(pw.x));
        float h2v = fast_tanh(acc.z + bf_lo(pw.y));
        float h3 = fast_tanh(acc.w + bf_hi(pw.y));
        uint2 hw;
        hw.x = pack_bf16(h0, h1);
        hw.y = pack_bf16(h2v, h3);
        ((uint2*)hout)[(size_t)r * 32 + i] = hw;   // h for next step == outT row (bf16)
    }
}

extern "C" void kernel_launch(void* const* d_in, const int* in_sizes, int n_in,
                              void* d_out, int out_size, void* d_ws, size_t ws_size,
                              hipStream_t stream) {
    const float* x        = (const float*)d_in[0];
    const int*   ih_idx   = (const int*)d_in[1];
    const float* ih_val   = (const float*)d_in[2];
    const int*   hh_idx   = (const int*)d_in[3];
    const float* hh_val   = (const float*)d_in[4];
    const float* bias_ih  = (const float*)d_in[5];
    const float* bias_hh  = (const float*)d_in[6];
    const int* ih_rows = ih_idx;
    const int* ih_cols = ih_idx + NNZ;
    const int* hh_rows = hh_idx;
    const int* hh_cols = hh_idx + NNZ;

    char* ws = (char*)d_ws;
    size_t off = 0;
    auto alloc = [&](size_t bytes) -> void* {
        void* p = ws + off;
        off += (bytes + 255) & ~(size_t)255;
        return p;
    };
    u32*   xTb     = (u32*)  alloc((size_t)T * H * 64 * 4);  // 128 MB bf16-packed x^T
    u32*   pre     = (u32*)  alloc((size_t)T * H * 64 * 4);  // 128 MB bf16-packed pre-activations
    u32*   outb    = (u32*)  alloc((size_t)T * H * 64 * 4);  // 128 MB bf16-packed h/outT
    int2*  pair_ih = (int2*) alloc((size_t)NNZ * 8);
    int2*  pair_hh = (int2*) alloc((size_t)NNZ * 8);
    int*   rp_ih   = (int*)  alloc((size_t)(H + 1) * 4);
    int*   rp_hh   = (int*)  alloc((size_t)(H + 1) * 4);
    int*   cnt_ih  = (int*)  alloc((size_t)H * 4);
    int*   cnt_hh  = (int*)  alloc((size_t)H * 4);
    int*   cur_ih  = (int*)  alloc((size_t)H * 4);
    int*   cur_hh  = (int*)  alloc((size_t)H * 4);

    hipMemsetAsync(cnt_ih, 0, (size_t)H * 4, stream);
    hipMemsetAsync(cnt_hh, 0, (size_t)H * 4, stream);

    const int tb = 256;
    const int gb = (NNZ + tb - 1) / tb;
    hist_kernel<<<gb, tb, 0, stream>>>(ih_rows, NNZ, cnt_ih);
    hist_kernel<<<gb, tb, 0, stream>>>(hh_rows, NNZ, cnt_hh);
    scan_kernel<<<2, 1024, 0, stream>>>(cnt_ih, rp_ih, cur_ih, cnt_hh, rp_hh, cur_hh);
    scatter_kernel<<<gb, tb, 0, stream>>>(ih_rows, ih_cols, ih_val, NNZ, cur_ih, pair_ih);
    scatter_kernel<<<gb, tb, 0, stream>>>(hh_rows, hh_cols, hh_val, NNZ, cur_hh, pair_hh);

    // x [B][T*H] fp32 -> xTb [T*H][64] bf16-pairs
    dim3 tblk(32, 8);
    dim3 tgrid1((T * H) / 32, B / 32);
    transpose_bf16_kernel<<<tgrid1, tblk, 0, stream>>>(x, xTb);

    // all-timestep ih spmm + bias
    ih_pre_kernel<<<T * H, 64, 0, stream>>>(rp_ih, pair_ih, xTb, pre, bias_ih, bias_hh);

    // sequential recurrence: step 0 is tanh(pre) only; step t gathers from outb[t-1]
    step_kernel<<<H / 4, 256, 0, stream>>>(rp_hh, pair_hh, (const u32*)nullptr,
                                           outb, pre);
    for (int t = 1; t < T; ++t) {
        step_kernel<<<H / 4, 256, 0, stream>>>(rp_hh, pair_hh,
                                               outb + (size_t)(t - 1) * H * 64,
                                               outb + (size_t)t * H * 64,
                                               pre + (size_t)t * H * 64);
    }

    // outb [T*H][64] bf16 -> d_out [B][T*H] f32
    dim3 tgrid2((T * H) / 32, 2);
    transpose_out_kernel<<<tgrid2, tblk, 0, stream>>>(outb, (float*)d_out);
}

// Round 10
// 2571.269 us; speedup vs baseline: 4.3457x; 1.0198x over previous
//
#include <hip/hip_runtime.h>
#include <cstdint>
#include <cstddef>
#include <cstring>

#define H 8192
#define NNZ 1000000
#define B 128
#define T 64

typedef unsigned int u32;
typedef u32 u32x2 __attribute__((ext_vector_type(2)));

__device__ inline float bf_lo(u32 w) { return __uint_as_float(w << 16); }
__device__ inline float bf_hi(u32 w) { return __uint_as_float(w & 0xffff0000u); }
__device__ inline unsigned short f2bf(float f) {        // RNE float->bf16
    u32 v = __float_as_uint(f);
    v += 0x7fffu + ((v >> 16) & 1u);
    return (unsigned short)(v >> 16);
}
__device__ inline u32 pack_bf16(float a, float b) {
    return (u32)f2bf(a) | ((u32)f2bf(b) << 16);
}
__device__ inline float fast_tanh(float x) {
    float e = __expf(2.0f * x);
    return 1.0f - 2.0f / (e + 1.0f);
}

// ---------------- CSR build ----------------
__global__ void hist_kernel(const int* __restrict__ rows, int nnz, int* __restrict__ count) {
    int j = blockIdx.x * blockDim.x + threadIdx.x;
    if (j < nnz) atomicAdd(&count[rows[j]], 1);
}

__global__ void scan_kernel(const int* __restrict__ cnt0, int* __restrict__ rp0, int* __restrict__ cur0,
                            const int* __restrict__ cnt1, int* __restrict__ rp1, int* __restrict__ cur1) {
    const int* cnt = (blockIdx.x == 0) ? cnt0 : cnt1;
    int* rp  = (blockIdx.x == 0) ? rp0 : rp1;
    int* cur = (blockIdx.x == 0) ? cur0 : cur1;
    __shared__ int buf[1024];
    __shared__ int carry;
    int tid = threadIdx.x;
    if (tid == 0) carry = 0;
    __syncthreads();
    for (int base = 0; base < H; base += 1024) {
        int v = cnt[base + tid];
        buf[tid] = v;
        __syncthreads();
        for (int off = 1; off < 1024; off <<= 1) {
            int t = (tid >= off) ? buf[tid - off] : 0;
            __syncthreads();
            buf[tid] += t;
            __syncthreads();
        }
        int incl = buf[tid];
        int excl = incl - v;
        int c = carry;
        rp[base + tid]  = c + excl;
        cur[base + tid] = c + excl;
        __syncthreads();
        if (tid == 1023) carry = c + incl;
        __syncthreads();
    }
    if (tid == 0) rp[H] = carry;
}

__global__ void scatter_kernel(const int* __restrict__ rows, const int* __restrict__ cols,
                               const float* __restrict__ vals, int nnz,
                               int* __restrict__ cursor, int2* __restrict__ opair) {
    int j = blockIdx.x * blockDim.x + threadIdx.x;
    if (j < nnz) {
        int r = rows[j];
        int p = atomicAdd(&cursor[r], 1);
        opair[p] = make_int2(cols[j], __float_as_int(vals[j]));
    }
}

// ---------------- transpose + bf16-pack: x [B][T*H] fp32 -> xTb [T*H][64] u32 (bf16 pairs) ----------------
__global__ void transpose_bf16_kernel(const float* __restrict__ src, u32* __restrict__ dst) {
    __shared__ float tile[32][33];
    int c0 = blockIdx.x * 32;    // T*H dim
    int r0 = blockIdx.y * 32;    // B dim
    int x = threadIdx.x, y = threadIdx.y;
    #pragma unroll
    for (int i = y; i < 32; i += 8) {
        tile[i][x] = src[(size_t)(r0 + i) * (T * H) + (c0 + x)];
    }
    __syncthreads();
    int tid = y * 32 + x;        // 256 threads, 512 words to write
    #pragma unroll
    for (int idx = tid; idx < 32 * 16; idx += 256) {
        int row = idx >> 4, w = idx & 15;
        u32 word = pack_bf16(tile[2 * w][row], tile[2 * w + 1][row]);
        dst[(size_t)(c0 + row) * 64 + (r0 >> 1) + w] = word;
    }
}

// ---------------- final transpose: outb [T*H][64] u32 (bf16 pairs) -> d_out [B][T*H] f32 ----------------
__global__ void transpose_out_kernel(const u32* __restrict__ src, float* __restrict__ dst) {
    __shared__ u32 tile[32][33];
    int c0 = blockIdx.x * 32;    // flat T*H index base
    int w0 = blockIdx.y * 32;    // u32-word (batch-pair) index base
    int x = threadIdx.x, y = threadIdx.y;
    #pragma unroll
    for (int i = y; i < 32; i += 8) {
        tile[i][x] = src[(size_t)(c0 + i) * 64 + (w0 + x)];
    }
    __syncthreads();
    #pragma unroll
    for (int i = y; i < 64; i += 8) {
        int w = i >> 1;
        u32 word = tile[x][w];
        float val = (i & 1) ? bf_hi(word) : bf_lo(word);
        dst[(size_t)(2 * w0 + i) * (size_t)(T * H) + (c0 + x)] = val;
    }
}

// ---------------- ih precompute: pre[t,h,:] = bias + spmm(ih, x_t), bf16-packed output ----------------
// 1 wave/row, blockIdx-only row derivation (scalar CSR stream), XCD swizzle (XCD k owns
// t in [8k,8k+8) so its 2MB x-slice stays L2-resident). Gathers: bf16, 2 columns per
// instruction (lane halves), 32-bit voffset + SGPR-base addressing, shfl_xor(32) combine.
// NOTE (R5/R8 post-mortem): per-CU line service ~2.4 cyc/line is pattern-independent
// (R4 2.3, R5 2.5, m13 copy 2.6) => ih line wall ~1000us at 4 lines/nnz. VALU co-wall
// (88% @ R8) attacked here via 32-bit addressing (64-bit VGPR addr chains -> 1 lshl_add).
__global__ void __launch_bounds__(64) ih_pre_kernel(
    const int* __restrict__ rp, const int2* __restrict__ pair,
    const u32* __restrict__ xTb, u32* __restrict__ pre,
    const float* __restrict__ bias_ih, const float* __restrict__ bias_hh) {
    int bid = blockIdx.x;
    int xcd = bid & 7;
    int i0  = bid >> 3;
    int t   = (xcd << 3) + (i0 >> 13);
    int r   = i0 & (H - 1);
    int lane = threadIdx.x;
    bool hi = lane >= 32;
    int i = lane & 31;
    const char* __restrict__ xtb = (const char*)(xTb + (size_t)t * H * 64);  // uniform base
    const u32 i8 = (u32)i * 8u;
    float ax = 0.f, ay = 0.f, az = 0.f, aw = 0.f;
    int s = rp[r], e = rp[r + 1];
    int j = s;
    for (; j + 16 <= e; j += 16) {
        int2 q[16];
        #pragma unroll
        for (int u = 0; u < 16; ++u) q[u] = pair[j + u];
        u32x2 g[8];
        #pragma unroll
        for (int u = 0; u < 8; ++u) {
            u32 c = (u32)(hi ? q[2 * u + 1].x : q[2 * u].x);
            g[u] = *(const u32x2*)(xtb + ((c << 8) + i8));
        }
        #pragma unroll
        for (int u = 0; u < 8; ++u) {
            float v = __int_as_float(hi ? q[2 * u + 1].y : q[2 * u].y);
            ax = fmaf(v, bf_lo(g[u].x), ax);
            ay = fmaf(v, bf_hi(g[u].x), ay);
            az = fmaf(v, bf_lo(g[u].y), az);
            aw = fmaf(v, bf_hi(g[u].y), aw);
        }
    }
    for (; j + 2 <= e; j += 2) {
        int2 q0 = pair[j], q1 = pair[j + 1];
        u32 c = (u32)(hi ? q1.x : q0.x);
        u32x2 g = *(const u32x2*)(xtb + ((c << 8) + i8));
        float v = __int_as_float(hi ? q1.y : q0.y);
        ax = fmaf(v, bf_lo(g.x), ax);
        ay = fmaf(v, bf_hi(g.x), ay);
        az = fmaf(v, bf_lo(g.y), az);
        aw = fmaf(v, bf_hi(g.y), aw);
    }
    if (j < e) {
        int2 q0 = pair[j];
        u32 c = (u32)q0.x;
        u32x2 g = *(const u32x2*)(xtb + ((c << 8) + i8));
        float v = hi ? 0.0f : __int_as_float(q0.y);
        ax = fmaf(v, bf_lo(g.x), ax);
        ay = fmaf(v, bf_hi(g.x), ay);
        az = fmaf(v, bf_lo(g.y), az);
        aw = fmaf(v, bf_hi(g.y), aw);
    }
    float tx = ax + __shfl_xor(ax, 32, 64);
    float ty = ay + __shfl_xor(ay, 32, 64);
    float tz = az + __shfl_xor(az, 32, 64);
    float tw = aw + __shfl_xor(aw, 32, 64);
    if (lane < 32) {
        float bias = bias_ih[r] + bias_hh[r];
        u32x2 pw;
        pw.x = pack_bf16(tx + bias, ty + bias);
        pw.y = pack_bf16(tz + bias, tw + bias);
        __builtin_nontemporal_store(pw, (u32x2*)(pre + ((size_t)t * H + r) * 64) + i);
    }
}

// ---------------- one recurrence step ----------------
// 4 waves/block, one row per wave (readfirstlane keeps CSR stream scalar). h lives ONLY
// in outb (bf16): step t writes outb[t] once; step t+1 gathers from it.
// hprev==nullptr => step 0 (h=0): tanh(pre) only.
__global__ void __launch_bounds__(256) step_kernel(
    const int* __restrict__ rp, const int2* __restrict__ pair,
    const u32* __restrict__ hprev, u32* __restrict__ hout,
    const u32* __restrict__ pre_t) {
    const int tid  = threadIdx.x;
    const int wav  = tid >> 6;
    const int lane = tid & 63;
    const bool hi  = lane >= 32;
    const int i    = lane & 31;
    const u32 i8   = (u32)i * 8u;
    const int r = __builtin_amdgcn_readfirstlane(((int)blockIdx.x << 2) + wav);
    // hoisted pre load: overlaps with gather latency
    u32x2 pw = __builtin_nontemporal_load((const u32x2*)pre_t + (size_t)r * 32 + i);
    float ax = 0.f, ay = 0.f, az = 0.f, aw = 0.f;
    if (hprev) {
        const char* __restrict__ hpb = (const char*)hprev;   // uniform base
        int s = rp[r], e = rp[r + 1];
        int j = s;
        for (; j + 16 <= e; j += 16) {
            int2 q[16];
            #pragma unroll
            for (int u = 0; u < 16; ++u) q[u] = pair[j + u];
            u32x2 g[8];
            #pragma unroll
            for (int u = 0; u < 8; ++u) {
                u32 c = (u32)(hi ? q[2 * u + 1].x : q[2 * u].x);
                g[u] = *(const u32x2*)(hpb + ((c << 8) + i8));
            }
            #pragma unroll
            for (int u = 0; u < 8; ++u) {
                float v = __int_as_float(hi ? q[2 * u + 1].y : q[2 * u].y);
                ax = fmaf(v, bf_lo(g[u].x), ax);
                ay = fmaf(v, bf_hi(g[u].x), ay);
                az = fmaf(v, bf_lo(g[u].y), az);
                aw = fmaf(v, bf_hi(g[u].y), aw);
            }
        }
        for (; j + 2 <= e; j += 2) {
            int2 q0 = pair[j], q1 = pair[j + 1];
            u32 c = (u32)(hi ? q1.x : q0.x);
            u32x2 g = *(const u32x2*)(hpb + ((c << 8) + i8));
            float v = __int_as_float(hi ? q1.y : q0.y);
            ax = fmaf(v, bf_lo(g.x), ax);
            ay = fmaf(v, bf_hi(g.x), ay);
            az = fmaf(v, bf_lo(g.y), az);
            aw = fmaf(v, bf_hi(g.y), aw);
        }
        if (j < e) {
            int2 q0 = pair[j];
            u32 c = (u32)q0.x;
            u32x2 g = *(const u32x2*)(hpb + ((c << 8) + i8));
            float v = hi ? 0.0f : __int_as_float(q0.y);
            ax = fmaf(v, bf_lo(g.x), ax);
            ay = fmaf(v, bf_hi(g.x), ay);
            az = fmaf(v, bf_lo(g.y), az);
            aw = fmaf(v, bf_hi(g.y), aw);
        }
        ax += __shfl_xor(ax, 32, 64);
        ay += __shfl_xor(ay, 32, 64);
        az += __shfl_xor(az, 32, 64);
        aw += __shfl_xor(aw, 32, 64);
    }
    if (lane < 32) {
        float h0 = fast_tanh(ax + bf_lo(pw.x));
        float h1 = fast_tanh(ay + bf_hi(pw.x));
        float h2v = fast_tanh(az + bf_lo(pw.y));
        float h3 = fast_tanh(aw + bf_hi(pw.y));
        u32x2 hw;
        hw.x = pack_bf16(h0, h1);
        hw.y = pack_bf16(h2v, h3);
        ((u32x2*)hout)[(size_t)r * 32 + i] = hw;   // h for next step == outT row (bf16)
    }
}

extern "C" void kernel_launch(void* const* d_in, const int* in_sizes, int n_in,
                              void* d_out, int out_size, void* d_ws, size_t ws_size,
                              hipStream_t stream) {
    const float* x        = (const float*)d_in[0];
    const int*   ih_idx   = (const int*)d_in[1];
    const float* ih_val   = (const float*)d_in[2];
    const int*   hh_idx   = (const int*)d_in[3];
    const float* hh_val   = (const float*)d_in[4];
    const float* bias_ih  = (const float*)d_in[5];
    const float* bias_hh  = (const float*)d_in[6];
    const int* ih_rows = ih_idx;
    const int* ih_cols = ih_idx + NNZ;
    const int* hh_rows = hh_idx;
    const int* hh_cols = hh_idx + NNZ;

    char* ws = (char*)d_ws;
    size_t off = 0;
    auto alloc = [&](size_t bytes) -> void* {
        void* p = ws + off;
        off += (bytes + 255) & ~(size_t)255;
        return p;
    };
    u32*   xTb     = (u32*)  alloc((size_t)T * H * 64 * 4);  // 128 MB bf16-packed x^T
    u32*   pre     = (u32*)  alloc((size_t)T * H * 64 * 4);  // 128 MB bf16-packed pre-activations
    u32*   outb    = (u32*)  alloc((size_t)T * H * 64 * 4);  // 128 MB bf16-packed h/outT
    int2*  pair_ih = (int2*) alloc((size_t)NNZ * 8);
    int2*  pair_hh = (int2*) alloc((size_t)NNZ * 8);
    int*   rp_ih   = (int*)  alloc((size_t)(H + 1) * 4);
    int*   rp_hh   = (int*)  alloc((size_t)(H + 1) * 4);
    int*   cnt_ih  = (int*)  alloc((size_t)H * 4);
    int*   cnt_hh  = (int*)  alloc((size_t)H * 4);
    int*   cur_ih  = (int*)  alloc((size_t)H * 4);
    int*   cur_hh  = (int*)  alloc((size_t)H * 4);

    hipMemsetAsync(cnt_ih, 0, (size_t)H * 4, stream);
    hipMemsetAsync(cnt_hh, 0, (size_t)H * 4, stream);

    const int tb = 256;
    const int gb = (NNZ + tb - 1) / tb;
    hist_kernel<<<gb, tb, 0, stream>>>(ih_rows, NNZ, cnt_ih);
    hist_kernel<<<gb, tb, 0, stream>>>(hh_rows, NNZ, cnt_hh);
    scan_kernel<<<2, 1024, 0, stream>>>(cnt_ih, rp_ih, cur_ih, cnt_hh, rp_hh, cur_hh);
    scatter_kernel<<<gb, tb, 0, stream>>>(ih_rows, ih_cols, ih_val, NNZ, cur_ih, pair_ih);
    scatter_kernel<<<gb, tb, 0, stream>>>(hh_rows, hh_cols, hh_val, NNZ, cur_hh, pair_hh);

    // x [B][T*H] fp32 -> xTb [T*H][64] bf16-pairs
    dim3 tblk(32, 8);
    dim3 tgrid1((T * H) / 32, B / 32);
    transpose_bf16_kernel<<<tgrid1, tblk, 0, stream>>>(x, xTb);

    // all-timestep ih spmm + bias
    ih_pre_kernel<<<T * H, 64, 0, stream>>>(rp_ih, pair_ih, xTb, pre, bias_ih, bias_hh);

    // sequential recurrence: step 0 is tanh(pre) only; step t gathers from outb[t-1]
    step_kernel<<<H / 4, 256, 0, stream>>>(rp_hh, pair_hh, (const u32*)nullptr,
                                           outb, pre);
    for (int t = 1; t < T; ++t) {
        step_kernel<<<H / 4, 256, 0, stream>>>(rp_hh, pair_hh,
                                               outb + (size_t)(t - 1) * H * 64,
                                               outb + (size_t)t * H * 64,
                                               pre + (size_t)t * H * 64);
    }

    // outb [T*H][64] bf16 -> d_out [B][T*H] f32
    dim3 tgrid2((T * H) / 32, 2);
    transpose_out_kernel<<<tgrid2, tblk, 0, stream>>>(outb, (float*)d_out);
}